// Round 3
// baseline (348.209 us; speedup 1.0000x reference)
//
#include <hip/hip_runtime.h>
#include <stdint.h>

#define N_NODES 20000
#define N_EDGES 320000
#define K_MIX 5
#define IN_F 256
#define OUT_F 128
#define NT 11              /* 1 + 2K column tiles of 128 */
#define TC (NT * OUT_F)    /* 1408 */
#define NCHUNK 4
#define CHUNK 5000         /* N_NODES / NCHUNK */

typedef __attribute__((ext_vector_type(8))) short short8;
typedef __attribute__((ext_vector_type(4))) float floatx4;

__device__ __forceinline__ unsigned short f2bf(float f) {
  union { float f; unsigned int i; } v;
  v.f = f;
  unsigned int x = v.i;
  unsigned int r = (x + 0x7fffu + ((x >> 16) & 1u)) >> 16;
  return (unsigned short)r;
}

__device__ __forceinline__ float exrelu(float mu, float sig) {
  // E[relu(X)], X ~ N(mu, sig) (sig is the variance). sig==0 -> relu(mu).
  if (sig < 1e-30f) return fmaxf(mu, 0.f);
  float ss = sqrtf(sig);
  float w = mu / ss;
  return ss * (expf(-0.5f * w * w) * 0.3989422804014327f +
               0.5f * w * (1.f + erff(w * 0.70710678118654752f)));
}

// ---------------- degree / norm ----------------
__global__ void k_deg(const int* __restrict__ row, int* __restrict__ deg) {
  int t = blockIdx.x * 256 + threadIdx.x;
  if (t < N_EDGES) atomicAdd(&deg[row[t]], 1);
}

__global__ void k_dinv(const int* __restrict__ deg, float* __restrict__ dinv) {
  int t = blockIdx.x * 256 + threadIdx.x;
  if (t < N_NODES) dinv[t] = rsqrtf((float)(deg[t] + 1));  // +1 self-loop
}

// ---------------- CSR build: 3-step scan + scatter ----------------
__global__ void k_scan1(const int* __restrict__ deg, int* __restrict__ startofs,
                        int* __restrict__ bsums) {
  __shared__ int sd[256];
  int t = threadIdx.x;
  int i = blockIdx.x * 256 + t;
  int v = (i < N_NODES) ? deg[i] : 0;
  sd[t] = v;
  __syncthreads();
  for (int off = 1; off < 256; off <<= 1) {
    int u = (t >= off) ? sd[t - off] : 0;
    __syncthreads();
    sd[t] += u;
    __syncthreads();
  }
  if (i < N_NODES) startofs[i] = sd[t] - v;  // chunk-local exclusive
  if (t == 255) bsums[blockIdx.x] = sd[255];
}

__global__ void k_scan2(int* __restrict__ bsums, int nb) {
  if (threadIdx.x == 0 && blockIdx.x == 0) {
    int run = 0;
    for (int b = 0; b < nb; b++) { int x = bsums[b]; bsums[b] = run; run += x; }
  }
}

__global__ void k_scan3(int* __restrict__ startofs, int* __restrict__ cursor,
                        const int* __restrict__ bsums) {
  int i = blockIdx.x * 256 + threadIdx.x;
  if (i < N_NODES) {
    int s0 = startofs[i] + bsums[blockIdx.x];
    startofs[i] = s0;
    cursor[i] = s0;
  }
}

__global__ void k_scatter(const int* __restrict__ row, const int* __restrict__ col,
                          const float* __restrict__ dinv, int* __restrict__ cursor,
                          int* __restrict__ csr_col, float* __restrict__ csr_w) {
  int t = blockIdx.x * 256 + threadIdx.x;
  if (t < N_EDGES) {
    int r = row[t], c = col[t];
    int p = atomicAdd(&cursor[r], 1);
    csr_col[p] = c;
    csr_w[p] = dinv[r] * dinv[c];
  }
}

// ---------------- B-matrix build: Bt[j][n][k] bf16 (transposed for MFMA B) ----
__global__ void k_buildB(const float* __restrict__ W, const float* __restrict__ means,
                         const float* __restrict__ logvars, unsigned short* __restrict__ Bt) {
  int idx = blockIdx.x * 256 + threadIdx.x;  // < 11*128*256
  int j = idx >> 15;
  int rem = idx & 32767;
  int n = rem >> 8;
  int kk = rem & 255;
  float wv = W[kk * OUT_F + n];
  float val;
  if (j == 0) val = wv;                                        // W
  else if (j <= 5) val = means[(j - 1) * IN_F + kk] * wv;      // means_k * W
  else val = expf(logvars[(j - 6) * IN_F + kk]) * wv * wv;     // var_k * W^2
  Bt[idx] = f2bf(val);
}

// ---------------- node prep: GMM responsibilities ----------------
__global__ void k_prep(const float* __restrict__ x, const float* __restrict__ logp,
                       const float* __restrict__ means, const float* __restrict__ logvars,
                       float* __restrict__ gamma) {
  __shared__ float s_mean[K_MIX * IN_F];
  __shared__ float s_rv[K_MIX * IN_F];
  int t = threadIdx.x;
  for (int j = t; j < K_MIX * IN_F; j += 256) {
    s_mean[j] = means[j];
    s_rv[j] = expf(-logvars[j]);  // 1/var
  }
  __syncthreads();
  int node = blockIdx.x * 4 + (t >> 6);
  int lane = t & 63;
  if (node >= N_NODES) return;
  float sum[K_MIX] = {0.f, 0.f, 0.f, 0.f, 0.f};
  for (int ii = 0; ii < 4; ii++) {
    int i = ii * 64 + lane;
    float xv = x[(size_t)node * IN_F + i];
    if (xv == xv) {
#pragma unroll
      for (int k = 0; k < K_MIX; k++) {
        float d = xv - s_mean[k * IN_F + i];
        sum[k] += d * d * s_rv[k * IN_F + i];
      }
    }
  }
#pragma unroll
  for (int k = 0; k < K_MIX; k++)
    for (int off = 32; off; off >>= 1) sum[k] += __shfl_xor(sum[k], off, 64);
  if (lane == 0) {
    float lg[K_MIX], mx = -1e30f;
#pragma unroll
    for (int k = 0; k < K_MIX; k++) {
      lg[k] = logp[k] - 0.5f * sum[k];
      mx = fmaxf(mx, lg[k]);
    }
    float se = 0.f;
#pragma unroll
    for (int k = 0; k < K_MIX; k++) { lg[k] = expf(lg[k] - mx); se += lg[k]; }
    float inv = 1.f / se;
#pragma unroll
    for (int k = 0; k < K_MIX; k++) gamma[node * K_MIX + k] = lg[k] * inv;
  }
}

// ---------------- fused 3-way SpMM: A@x0 | A@m | A2@m  (one wave per node) -----
// Gathers fp32 x directly; derives x0 and NaN-mask on the fly. Emits bf16 G.
__global__ void k_spmm(const float* __restrict__ x, const int* __restrict__ startofs,
                       const int* __restrict__ deg, const float* __restrict__ dinv,
                       const int* __restrict__ csr_col, const float* __restrict__ csr_w,
                       unsigned short* __restrict__ G, float* __restrict__ sArr,
                       int base, int cnt) {
  int t = threadIdx.x;
  int local = blockIdx.x * 4 + (t >> 6);
  if (local >= cnt) return;
  int node = base + local;
  int lane = t & 63;
  float ax[4] = {0, 0, 0, 0}, am[4] = {0, 0, 0, 0}, am2[4] = {0, 0, 0, 0};
  float di = dinv[node];
  float ws = di * di, ws2 = ws * ws;
  {  // self-loop
    float4 xv = *(const float4*)(x + (size_t)node * IN_F + 4 * lane);
    float xf[4] = {xv.x, xv.y, xv.z, xv.w};
#pragma unroll
    for (int j = 0; j < 4; j++) {
      bool nn = (xf[j] != xf[j]);
      float x0 = nn ? 0.f : xf[j];
      float mf = nn ? 1.f : 0.f;
      ax[j] += ws * x0;
      am[j] += ws * mf;
      am2[j] += ws2 * mf;
    }
  }
  float ssum = ws;
  int st = startofs[node], len = deg[node];
  for (int e = 0; e < len; e++) {
    int c = csr_col[st + e];
    float w = csr_w[st + e], w2 = w * w;
    float4 xv = *(const float4*)(x + (size_t)c * IN_F + 4 * lane);
    float xf[4] = {xv.x, xv.y, xv.z, xv.w};
#pragma unroll
    for (int j = 0; j < 4; j++) {
      bool nn = (xf[j] != xf[j]);
      float x0 = nn ? 0.f : xf[j];
      float mf = nn ? 1.f : 0.f;
      ax[j] += w * x0;
      am[j] += w * mf;
      am2[j] += w2 * mf;
    }
    ssum += w;
  }
  ushort4 o;
  o.x = f2bf(ax[0]); o.y = f2bf(ax[1]); o.z = f2bf(ax[2]); o.w = f2bf(ax[3]);
  *(ushort4*)(G + (size_t)local * 768 + 4 * lane) = o;
  o.x = f2bf(am[0]); o.y = f2bf(am[1]); o.z = f2bf(am[2]); o.w = f2bf(am[3]);
  *(ushort4*)(G + (size_t)local * 768 + 256 + 4 * lane) = o;
  o.x = f2bf(am2[0]); o.y = f2bf(am2[1]); o.z = f2bf(am2[2]); o.w = f2bf(am2[3]);
  *(ushort4*)(G + (size_t)local * 768 + 512 + 4 * lane) = o;
  if (lane == 0) sArr[node] = ssum;
}

// ---------------- MFMA GEMM: T[lrow][jt*128+c] = (G cols aoff..aoff+256)@B_jt --
__global__ __launch_bounds__(256) void k_gemm(const unsigned short* __restrict__ G,
                                              const unsigned short* __restrict__ Bt,
                                              float* __restrict__ T, int cnt) {
  int mt = blockIdx.x, jt = blockIdx.y;
  int t = threadIdx.x, wave = t >> 6, lane = t & 63;
  int wr = wave >> 1, wc = wave & 1;
  int quad = lane >> 4, l16 = lane & 15;
  int aoff = (jt == 0) ? 0 : (jt <= 5 ? 256 : 512);
  const unsigned short* Ap = G + aoff;
  const unsigned short* Bp = Bt + jt * (128 * 256);
  int arow[4], brow[4];
#pragma unroll
  for (int mi = 0; mi < 4; mi++) {
    int r = mt * 128 + wr * 64 + mi * 16 + l16;
    arow[mi] = (r < cnt) ? r : (cnt - 1);
  }
#pragma unroll
  for (int ni = 0; ni < 4; ni++) brow[ni] = wc * 64 + ni * 16 + l16;
  floatx4 acc[4][4];
  floatx4 z = {0.f, 0.f, 0.f, 0.f};
#pragma unroll
  for (int mi = 0; mi < 4; mi++)
#pragma unroll
    for (int ni = 0; ni < 4; ni++) acc[mi][ni] = z;

  for (int k0 = 0; k0 < 256; k0 += 32) {
    short8 a[4], b[4];
#pragma unroll
    for (int mi = 0; mi < 4; mi++)
      a[mi] = *(const short8*)(Ap + (size_t)arow[mi] * 768 + k0 + quad * 8);
#pragma unroll
    for (int ni = 0; ni < 4; ni++)
      b[ni] = *(const short8*)(Bp + (size_t)brow[ni] * 256 + k0 + quad * 8);
#pragma unroll
    for (int mi = 0; mi < 4; mi++)
#pragma unroll
      for (int ni = 0; ni < 4; ni++)
        acc[mi][ni] = __builtin_amdgcn_mfma_f32_16x16x32_bf16(a[mi], b[ni], acc[mi][ni], 0, 0, 0);
  }
#pragma unroll
  for (int mi = 0; mi < 4; mi++)
#pragma unroll
    for (int ni = 0; ni < 4; ni++) {
      int gc = jt * 128 + wc * 64 + ni * 16 + l16;
#pragma unroll
      for (int reg = 0; reg < 4; reg++) {
        int gr = mt * 128 + wr * 64 + mi * 16 + quad * 4 + reg;
        if (gr < cnt) T[(size_t)gr * TC + gc] = acc[mi][ni][reg];
      }
    }
}

// ---------------- epilogue: Ex_relu + gamma-weighted combine ----------------
__global__ void k_final(const float* __restrict__ T, const float* __restrict__ gamma,
                        const float* __restrict__ sArr, const float* __restrict__ bias,
                        float* __restrict__ out, int base, int cnt) {
  int t = threadIdx.x;
  int local = blockIdx.x * 4 + (t >> 6);
  if (local >= cnt) return;
  int node = base + local;
  int lane = t & 63;
  int o0 = 2 * lane;
  float g[K_MIX];
#pragma unroll
  for (int k = 0; k < K_MIX; k++) g[k] = gamma[node * K_MIX + k];
  float sv = sArr[node];
  float b0 = bias[o0], b1 = bias[o0 + 1];
  const float* Tr = T + (size_t)local * TC;
  float cx0 = Tr[o0], cx1 = Tr[o0 + 1];
  float a0 = 0.f, a1 = 0.f;
#pragma unroll
  for (int k = 0; k < K_MIX; k++) {
    float tm0 = Tr[128 * (1 + k) + o0], tm1 = Tr[128 * (1 + k) + o0 + 1];
    float tv0 = Tr[128 * (6 + k) + o0], tv1 = Tr[128 * (6 + k) + o0 + 1];
    float mu0 = cx0 + tm0 + b0 * sv;
    float mu1 = cx1 + tm1 + b1 * sv;
    a0 += g[k] * exrelu(mu0, tv0);
    a1 += g[k] * exrelu(mu1, tv1);
  }
  float2 ov = {a0, a1};
  *(float2*)(out + (size_t)node * OUT_F + o0) = ov;
}

extern "C" void kernel_launch(void* const* d_in, const int* in_sizes, int n_in,
                              void* d_out, int out_size, void* d_ws, size_t ws_size,
                              hipStream_t stream) {
  const float* x = (const float*)d_in[0];
  const int* ei = (const int*)d_in[1];
  const float* logp = (const float*)d_in[2];
  const float* means = (const float*)d_in[3];
  const float* lvar = (const float*)d_in[4];
  const float* W = (const float*)d_in[5];
  const float* bias = (const float*)d_in[6];
  float* out = (float*)d_out;
  const int* row = ei;
  const int* col = ei + N_EDGES;

  char* p = (char*)d_ws;
  auto alloc = [&](size_t bytes) -> char* {
    char* q = p;
    p += (bytes + 255) & ~((size_t)255);
    return q;
  };
  // total ~40 MB
  int* deg = (int*)alloc(N_NODES * 4);
  float* dinv = (float*)alloc(N_NODES * 4);
  int* startofs = (int*)alloc(N_NODES * 4);
  int* cursor = (int*)alloc(N_NODES * 4);
  int* bsums = (int*)alloc(128 * 4);
  int* csr_col = (int*)alloc((size_t)N_EDGES * 4);
  float* csr_w = (float*)alloc((size_t)N_EDGES * 4);
  float* gamma = (float*)alloc((size_t)N_NODES * K_MIX * 4);
  float* sArr = (float*)alloc(N_NODES * 4);
  unsigned short* Bt = (unsigned short*)alloc((size_t)NT * 128 * 256 * 2);
  unsigned short* G = (unsigned short*)alloc((size_t)CHUNK * 768 * 2);
  float* T = (float*)alloc((size_t)CHUNK * TC * 4);

  hipMemsetAsync(deg, 0, N_NODES * 4, stream);
  k_deg<<<(N_EDGES + 255) / 256, 256, 0, stream>>>(row, deg);
  k_dinv<<<(N_NODES + 255) / 256, 256, 0, stream>>>(deg, dinv);
  k_scan1<<<79, 256, 0, stream>>>(deg, startofs, bsums);
  k_scan2<<<1, 1, 0, stream>>>(bsums, 79);
  k_scan3<<<79, 256, 0, stream>>>(startofs, cursor, bsums);
  k_scatter<<<(N_EDGES + 255) / 256, 256, 0, stream>>>(row, col, dinv, cursor, csr_col, csr_w);
  k_buildB<<<(NT * 128 * 256) / 256, 256, 0, stream>>>(W, means, lvar, Bt);
  k_prep<<<N_NODES / 4, 256, 0, stream>>>(x, logp, means, lvar, gamma);

  for (int c = 0; c < NCHUNK; c++) {
    int base = c * CHUNK;
    int cnt = CHUNK;
    k_spmm<<<(cnt + 3) / 4, 256, 0, stream>>>(x, startofs, deg, dinv, csr_col, csr_w,
                                              G, sArr, base, cnt);
    k_gemm<<<dim3((cnt + 127) / 128, NT), 256, 0, stream>>>(G, Bt, T, cnt);
    k_final<<<(cnt + 3) / 4, 256, 0, stream>>>(T, gamma, sArr, bias, out, base, cnt);
  }
}

// Round 4
// 280.276 us; speedup vs baseline: 1.2424x; 1.2424x over previous
//
#include <hip/hip_runtime.h>
#include <stdint.h>

#define N_NODES 20000
#define N_EDGES 320000
#define K_MIX 5
#define IN_F 256
#define OUT_F 128
#define NT 11              /* 1 + 2K column tiles of 128 */
#define TC (NT * OUT_F)    /* 1408 */

typedef __attribute__((ext_vector_type(8))) short short8;
typedef __attribute__((ext_vector_type(4))) float floatx4;

__device__ __forceinline__ float bf2f(unsigned int u) {
  union { unsigned int i; float f; } v;
  v.i = (u & 0xffffu) << 16;
  return v.f;
}
__device__ __forceinline__ unsigned short f2bf(float f) {
  union { float f; unsigned int i; } v;
  v.f = f;
  unsigned int x = v.i;
  unsigned int r = (x + 0x7fffu + ((x >> 16) & 1u)) >> 16;
  return (unsigned short)r;
}

__device__ __forceinline__ float exrelu(float mu, float sig) {
  // E[relu(X)], X ~ N(mu, sig) (sig is the variance). sig==0 -> relu(mu).
  if (sig < 1e-30f) return fmaxf(mu, 0.f);
  float ss = sqrtf(sig);
  float w = mu / ss;
  return ss * (expf(-0.5f * w * w) * 0.3989422804014327f +
               0.5f * w * (1.f + erff(w * 0.70710678118654752f)));
}

// ---------------- degree ----------------
__global__ void k_deg(const int* __restrict__ row, int* __restrict__ deg) {
  int t = blockIdx.x * 256 + threadIdx.x;
  if (t < N_EDGES) atomicAdd(&deg[row[t]], 1);
}

// ---------------- CSR build: scan (+dinv fused) + scatter ----------------
__global__ void k_scan1(const int* __restrict__ deg, int* __restrict__ startofs,
                        int* __restrict__ bsums, float* __restrict__ dinv) {
  __shared__ int sd[256];
  int t = threadIdx.x;
  int i = blockIdx.x * 256 + t;
  int v = (i < N_NODES) ? deg[i] : 0;
  if (i < N_NODES) dinv[i] = rsqrtf((float)(v + 1));  // +1 self-loop
  sd[t] = v;
  __syncthreads();
  for (int off = 1; off < 256; off <<= 1) {
    int u = (t >= off) ? sd[t - off] : 0;
    __syncthreads();
    sd[t] += u;
    __syncthreads();
  }
  if (i < N_NODES) startofs[i] = sd[t] - v;  // chunk-local exclusive
  if (t == 255) bsums[blockIdx.x] = sd[255];
}

__global__ void k_scan2(int* __restrict__ bsums, int nb) {
  if (threadIdx.x == 0 && blockIdx.x == 0) {
    int run = 0;
    for (int b = 0; b < nb; b++) { int x = bsums[b]; bsums[b] = run; run += x; }
  }
}

__global__ void k_scan3(int* __restrict__ startofs, int* __restrict__ cursor,
                        const int* __restrict__ bsums) {
  int i = blockIdx.x * 256 + threadIdx.x;
  if (i < N_NODES) {
    int s0 = startofs[i] + bsums[blockIdx.x];
    startofs[i] = s0;
    cursor[i] = s0;
  }
}

__global__ void k_scatter(const int* __restrict__ row, const int* __restrict__ col,
                          const float* __restrict__ dinv, int* __restrict__ cursor,
                          int* __restrict__ csr_col, float* __restrict__ csr_w) {
  int t = blockIdx.x * 256 + threadIdx.x;
  if (t < N_EDGES) {
    int r = row[t], c = col[t];
    int p = atomicAdd(&cursor[r], 1);
    csr_col[p] = c;
    csr_w[p] = dinv[r] * dinv[c];
  }
}

// ---------------- B-matrix build: Bt[j][n][k] bf16 (transposed for MFMA B) ----
__global__ void k_buildB(const float* __restrict__ W, const float* __restrict__ means,
                         const float* __restrict__ logvars, unsigned short* __restrict__ Bt) {
  int idx = blockIdx.x * 256 + threadIdx.x;  // < 11*128*256
  int j = idx >> 15;
  int rem = idx & 32767;
  int n = rem >> 8;
  int kk = rem & 255;
  float wv = W[kk * OUT_F + n];
  float val;
  if (j == 0) val = wv;                                        // W
  else if (j <= 5) val = means[(j - 1) * IN_F + kk] * wv;      // means_k * W
  else val = expf(logvars[(j - 6) * IN_F + kk]) * wv * wv;     // var_k * W^2
  Bt[idx] = f2bf(val);
}

// ---------------- node prep: GMM responsibilities ----------------
__global__ void k_prep(const float* __restrict__ x, const float* __restrict__ logp,
                       const float* __restrict__ means, const float* __restrict__ logvars,
                       float* __restrict__ gamma) {
  __shared__ float s_mean[K_MIX * IN_F];
  __shared__ float s_rv[K_MIX * IN_F];
  int t = threadIdx.x;
  for (int j = t; j < K_MIX * IN_F; j += 256) {
    s_mean[j] = means[j];
    s_rv[j] = expf(-logvars[j]);  // 1/var
  }
  __syncthreads();
  int node = blockIdx.x * 4 + (t >> 6);
  int lane = t & 63;
  if (node >= N_NODES) return;
  float sum[K_MIX] = {0.f, 0.f, 0.f, 0.f, 0.f};
  for (int ii = 0; ii < 4; ii++) {
    int i = ii * 64 + lane;
    float xv = x[(size_t)node * IN_F + i];
    if (xv == xv) {
#pragma unroll
      for (int k = 0; k < K_MIX; k++) {
        float d = xv - s_mean[k * IN_F + i];
        sum[k] += d * d * s_rv[k * IN_F + i];
      }
    }
  }
#pragma unroll
  for (int k = 0; k < K_MIX; k++)
    for (int off = 32; off; off >>= 1) sum[k] += __shfl_xor(sum[k], off, 64);
  if (lane == 0) {
    float lg[K_MIX], mx = -1e30f;
#pragma unroll
    for (int k = 0; k < K_MIX; k++) {
      lg[k] = logp[k] - 0.5f * sum[k];
      mx = fmaxf(mx, lg[k]);
    }
    float se = 0.f;
#pragma unroll
    for (int k = 0; k < K_MIX; k++) { lg[k] = expf(lg[k] - mx); se += lg[k]; }
    float inv = 1.f / se;
#pragma unroll
    for (int k = 0; k < K_MIX; k++) gamma[node * K_MIX + k] = lg[k] * inv;
  }
}

// ---------------- fused 3-way SpMM: A@x0 | A@m | A2@m  (one wave per node) -----
// Gathers fp32 x directly; derives x0 and NaN-mask on the fly. Emits bf16 G.
__global__ void k_spmm(const float* __restrict__ x, const int* __restrict__ startofs,
                       const int* __restrict__ deg, const float* __restrict__ dinv,
                       const int* __restrict__ csr_col, const float* __restrict__ csr_w,
                       unsigned short* __restrict__ G, float* __restrict__ sArr) {
  int t = threadIdx.x;
  int node = blockIdx.x * 4 + (t >> 6);
  if (node >= N_NODES) return;
  int lane = t & 63;
  float ax[4] = {0, 0, 0, 0}, am[4] = {0, 0, 0, 0}, am2[4] = {0, 0, 0, 0};
  float di = dinv[node];
  float ws = di * di, ws2 = ws * ws;
  {  // self-loop
    float4 xv = *(const float4*)(x + (size_t)node * IN_F + 4 * lane);
    float xf[4] = {xv.x, xv.y, xv.z, xv.w};
#pragma unroll
    for (int j = 0; j < 4; j++) {
      bool nn = (xf[j] != xf[j]);
      float x0 = nn ? 0.f : xf[j];
      float mf = nn ? 1.f : 0.f;
      ax[j] += ws * x0;
      am[j] += ws * mf;
      am2[j] += ws2 * mf;
    }
  }
  float ssum = ws;
  int st = startofs[node], len = deg[node];
  int c_nxt = 0; float w_nxt = 0.f;
  if (len > 0) { c_nxt = csr_col[st]; w_nxt = csr_w[st]; }
  for (int e = 0; e < len; e++) {
    int c = c_nxt;
    float w = w_nxt;
    if (e + 1 < len) { c_nxt = csr_col[st + e + 1]; w_nxt = csr_w[st + e + 1]; }
    float w2 = w * w;
    float4 xv = *(const float4*)(x + (size_t)c * IN_F + 4 * lane);
    float xf[4] = {xv.x, xv.y, xv.z, xv.w};
#pragma unroll
    for (int j = 0; j < 4; j++) {
      bool nn = (xf[j] != xf[j]);
      float x0 = nn ? 0.f : xf[j];
      float mf = nn ? 1.f : 0.f;
      ax[j] += w * x0;
      am[j] += w * mf;
      am2[j] += w2 * mf;
    }
    ssum += w;
  }
  ushort4 o;
  o.x = f2bf(ax[0]); o.y = f2bf(ax[1]); o.z = f2bf(ax[2]); o.w = f2bf(ax[3]);
  *(ushort4*)(G + (size_t)node * 768 + 4 * lane) = o;
  o.x = f2bf(am[0]); o.y = f2bf(am[1]); o.z = f2bf(am[2]); o.w = f2bf(am[3]);
  *(ushort4*)(G + (size_t)node * 768 + 256 + 4 * lane) = o;
  o.x = f2bf(am2[0]); o.y = f2bf(am2[1]); o.z = f2bf(am2[2]); o.w = f2bf(am2[3]);
  *(ushort4*)(G + (size_t)node * 768 + 512 + 4 * lane) = o;
  if (lane == 0) sArr[node] = ssum;
}

// ---------------- MFMA GEMM: T[r][jt*128+c] = (G cols aoff..aoff+256) @ B_jt ---
__global__ __launch_bounds__(256) void k_gemm(const unsigned short* __restrict__ G,
                                              const unsigned short* __restrict__ Bt,
                                              unsigned short* __restrict__ T) {
  int mt = blockIdx.x, jt = blockIdx.y;
  int t = threadIdx.x, wave = t >> 6, lane = t & 63;
  int wr = wave >> 1, wc = wave & 1;
  int quad = lane >> 4, l16 = lane & 15;
  int aoff = (jt == 0) ? 0 : (jt <= 5 ? 256 : 512);
  const unsigned short* Ap = G + aoff;
  const unsigned short* Bp = Bt + jt * (128 * 256);
  int arow[4], brow[4];
#pragma unroll
  for (int mi = 0; mi < 4; mi++) {
    int r = mt * 128 + wr * 64 + mi * 16 + l16;
    arow[mi] = (r < N_NODES) ? r : (N_NODES - 1);
  }
#pragma unroll
  for (int ni = 0; ni < 4; ni++) brow[ni] = wc * 64 + ni * 16 + l16;
  floatx4 acc[4][4];
  floatx4 z = {0.f, 0.f, 0.f, 0.f};
#pragma unroll
  for (int mi = 0; mi < 4; mi++)
#pragma unroll
    for (int ni = 0; ni < 4; ni++) acc[mi][ni] = z;

  for (int k0 = 0; k0 < 256; k0 += 32) {
    short8 a[4], b[4];
#pragma unroll
    for (int mi = 0; mi < 4; mi++)
      a[mi] = *(const short8*)(Ap + (size_t)arow[mi] * 768 + k0 + quad * 8);
#pragma unroll
    for (int ni = 0; ni < 4; ni++)
      b[ni] = *(const short8*)(Bp + (size_t)brow[ni] * 256 + k0 + quad * 8);
#pragma unroll
    for (int mi = 0; mi < 4; mi++)
#pragma unroll
      for (int ni = 0; ni < 4; ni++)
        acc[mi][ni] = __builtin_amdgcn_mfma_f32_16x16x32_bf16(a[mi], b[ni], acc[mi][ni], 0, 0, 0);
  }
#pragma unroll
  for (int mi = 0; mi < 4; mi++)
#pragma unroll
    for (int ni = 0; ni < 4; ni++) {
      int gc = jt * 128 + wc * 64 + ni * 16 + l16;
#pragma unroll
      for (int reg = 0; reg < 4; reg++) {
        int gr = mt * 128 + wr * 64 + mi * 16 + quad * 4 + reg;
        if (gr < N_NODES) T[(size_t)gr * TC + gc] = f2bf(acc[mi][ni][reg]);
      }
    }
}

// ---------------- epilogue: Ex_relu + gamma-weighted combine ----------------
__global__ void k_final(const unsigned short* __restrict__ T, const float* __restrict__ gamma,
                        const float* __restrict__ sArr, const float* __restrict__ bias,
                        float* __restrict__ out) {
  int t = threadIdx.x;
  int node = blockIdx.x * 4 + (t >> 6);
  if (node >= N_NODES) return;
  int lane = t & 63;
  int o0 = 2 * lane;
  float g[K_MIX];
#pragma unroll
  for (int k = 0; k < K_MIX; k++) g[k] = gamma[node * K_MIX + k];
  float sv = sArr[node];
  float b0 = bias[o0], b1 = bias[o0 + 1];
  const unsigned short* Tr = T + (size_t)node * TC;
  unsigned int c0u = *(const unsigned int*)(Tr + o0);
  float cx0 = bf2f(c0u), cx1 = bf2f(c0u >> 16);
  float a0 = 0.f, a1 = 0.f;
#pragma unroll
  for (int k = 0; k < K_MIX; k++) {
    unsigned int tm = *(const unsigned int*)(Tr + 128 * (1 + k) + o0);
    unsigned int tv = *(const unsigned int*)(Tr + 128 * (6 + k) + o0);
    float mu0 = cx0 + bf2f(tm) + b0 * sv;
    float mu1 = cx1 + bf2f(tm >> 16) + b1 * sv;
    a0 += g[k] * exrelu(mu0, bf2f(tv));
    a1 += g[k] * exrelu(mu1, bf2f(tv >> 16));
  }
  float2 ov = {a0, a1};
  *(float2*)(out + (size_t)node * OUT_F + o0) = ov;
}

extern "C" void kernel_launch(void* const* d_in, const int* in_sizes, int n_in,
                              void* d_out, int out_size, void* d_ws, size_t ws_size,
                              hipStream_t stream) {
  const float* x = (const float*)d_in[0];
  const int* ei = (const int*)d_in[1];
  const float* logp = (const float*)d_in[2];
  const float* means = (const float*)d_in[3];
  const float* lvar = (const float*)d_in[4];
  const float* W = (const float*)d_in[5];
  const float* bias = (const float*)d_in[6];
  float* out = (float*)d_out;
  const int* row = ei;
  const int* col = ei + N_EDGES;

  char* p = (char*)d_ws;
  auto alloc = [&](size_t bytes) -> char* {
    char* q = p;
    p += (bytes + 255) & ~((size_t)255);
    return q;
  };
  // total ~91 MB (ws is 256 MiB)
  int* deg = (int*)alloc(N_NODES * 4);
  float* dinv = (float*)alloc(N_NODES * 4);
  int* startofs = (int*)alloc(N_NODES * 4);
  int* cursor = (int*)alloc(N_NODES * 4);
  int* bsums = (int*)alloc(128 * 4);
  int* csr_col = (int*)alloc((size_t)N_EDGES * 4);
  float* csr_w = (float*)alloc((size_t)N_EDGES * 4);
  float* gamma = (float*)alloc((size_t)N_NODES * K_MIX * 4);
  float* sArr = (float*)alloc(N_NODES * 4);
  unsigned short* Bt = (unsigned short*)alloc((size_t)NT * 128 * 256 * 2);
  unsigned short* G = (unsigned short*)alloc((size_t)N_NODES * 768 * 2);
  unsigned short* T = (unsigned short*)alloc((size_t)N_NODES * TC * 2);

  hipMemsetAsync(deg, 0, N_NODES * 4, stream);
  k_deg<<<(N_EDGES + 255) / 256, 256, 0, stream>>>(row, deg);
  k_scan1<<<79, 256, 0, stream>>>(deg, startofs, bsums, dinv);
  k_scan2<<<1, 1, 0, stream>>>(bsums, 79);
  k_scan3<<<79, 256, 0, stream>>>(startofs, cursor, bsums);
  k_scatter<<<(N_EDGES + 255) / 256, 256, 0, stream>>>(row, col, dinv, cursor, csr_col, csr_w);
  k_buildB<<<(NT * 128 * 256) / 256, 256, 0, stream>>>(W, means, lvar, Bt);
  k_prep<<<N_NODES / 4, 256, 0, stream>>>(x, logp, means, lvar, gamma);
  k_spmm<<<N_NODES / 4, 256, 0, stream>>>(x, startofs, deg, dinv, csr_col, csr_w, G, sArr);
  k_gemm<<<dim3((N_NODES + 127) / 128, NT), 256, 0, stream>>>(G, Bt, T);
  k_final<<<N_NODES / 4, 256, 0, stream>>>(T, gamma, sArr, bias, out);
}